// Round 6
// baseline (1533.566 us; speedup 1.0000x reference)
//
#include <hip/hip_runtime.h>
#include <hip/hip_bf16.h>

// GRU: V=50000, E=256, H=256, B=64, T=512
// out: outputs[T,B,H] f32 then h_last[1,B,H] f32 (concat flat)

#define T_SEQ 512
#define B_SZ 64
#define E_DIM 256
#define H_DIM 256
#define G3 768   // 3*H

typedef _Float16 half2v __attribute__((ext_vector_type(2)));

#if __has_builtin(__builtin_amdgcn_fdot2)
#define FDOT2(a, b, c) __builtin_amdgcn_fdot2((a), (b), (c), false)
#else
#define FDOT2(a, b, c) ((c) + (float)(a).x * (float)(b).x + (float)(a).y * (float)(b).y)
#endif

// ---------------- Kernel A: x_proj = gather(emb, input) @ W_ih^T + b_ih ----
// Also folds b_hh for the r/z gates (cols < 512) into xp. The n-gate b_hh
// part must NOT be folded (reference: n = tanh(xn + r*(W_n h + b_hh_n))).
#define BM 64
#define BN 64
#define BK 32
#define LDSPAD 4

__global__ __launch_bounds__(256) void xproj_kernel(
    const int* __restrict__ input,
    const float* __restrict__ emb,
    const float* __restrict__ W_ih,
    const float* __restrict__ b_ih,
    const float* __restrict__ b_hh,
    float* __restrict__ xp)
{
    __shared__ float As[BM][BK + LDSPAD];
    __shared__ float Bs[BN][BK + LDSPAD];
    __shared__ int rowidx[BM];

    const int tid = threadIdx.x;
    const int m0 = blockIdx.x * BM;
    const int n0 = blockIdx.y * BN;

    if (tid < BM) {
        int m = m0 + tid;
        int t = m >> 6;
        int b = m & 63;
        rowidx[tid] = input[b * T_SEQ + t];
    }
    __syncthreads();

    float acc[4][4] = {};
    const int ty = tid >> 4;
    const int tx = tid & 15;

    for (int k0 = 0; k0 < E_DIM; k0 += BK) {
        #pragma unroll
        for (int i = 0; i < 2; ++i) {
            int f4 = tid * 2 + i;
            int row = f4 >> 3;
            int c4  = (f4 & 7) * 4;
            float4 v = *reinterpret_cast<const float4*>(
                emb + (size_t)rowidx[row] * E_DIM + k0 + c4);
            *reinterpret_cast<float4*>(&As[row][c4]) = v;
        }
        #pragma unroll
        for (int i = 0; i < 2; ++i) {
            int f4 = tid * 2 + i;
            int row = f4 >> 3;
            int c4  = (f4 & 7) * 4;
            float4 v = *reinterpret_cast<const float4*>(
                W_ih + (size_t)(n0 + row) * E_DIM + k0 + c4);
            *reinterpret_cast<float4*>(&Bs[row][c4]) = v;
        }
        __syncthreads();

        #pragma unroll
        for (int kk = 0; kk < BK; kk += 4) {
            float4 a[4], b[4];
            #pragma unroll
            for (int i = 0; i < 4; ++i)
                a[i] = *reinterpret_cast<const float4*>(&As[ty * 4 + i][kk]);
            #pragma unroll
            for (int j = 0; j < 4; ++j)
                b[j] = *reinterpret_cast<const float4*>(&Bs[tx * 4 + j][kk]);
            #pragma unroll
            for (int i = 0; i < 4; ++i)
                #pragma unroll
                for (int j = 0; j < 4; ++j)
                    acc[i][j] += a[i].x * b[j].x + a[i].y * b[j].y +
                                 a[i].z * b[j].z + a[i].w * b[j].w;
        }
        __syncthreads();
    }

    const bool foldbh = (n0 < 512);   // whole 64-wide tile is one gate region
    #pragma unroll
    for (int i = 0; i < 4; ++i) {
        int m = m0 + ty * 4 + i;
        int n = n0 + tx * 4;
        float4 o;
        o.x = acc[i][0] + b_ih[n + 0] + (foldbh ? b_hh[n + 0] : 0.0f);
        o.y = acc[i][1] + b_ih[n + 1] + (foldbh ? b_hh[n + 1] : 0.0f);
        o.z = acc[i][2] + b_ih[n + 2] + (foldbh ? b_hh[n + 2] : 0.0f);
        o.w = acc[i][3] + b_ih[n + 3] + (foldbh ? b_hh[n + 3] : 0.0f);
        *reinterpret_cast<float4*>(&xp[(size_t)m * G3 + n]) = o;
    }
}

// ---------------- Kernel B: GRU scan, 96 resident words/thread -------------
// 64 blocks (one per batch), 1024 threads = 16 waves, waves_per_eu(4,4)
// => 128-VGPR cap, which is ALSO the allocator's natural target: total live
// set ~128 regs, so no spill fight (R2-R4 lesson: footprint>target loses).
// Thread (jj = tid>>3, q = tid&7) owns rows {jj+128s, s=0..5} x k-halves
// [32q,32q+32) = 96 packed-f16 words. 8-lane shfl_xor reduce.
// LDS h chunk reads rotated by (q>>1)&3 so the 8 q-lanes' ds_read_b128 hit
// disjoint bank slots; weights loaded pre-rotated (static reg indices).
__device__ __forceinline__ float fast_sigmoid(float x) {
    float e = __expf(-x);
    return __builtin_amdgcn_rcpf(1.0f + e);
}
__device__ __forceinline__ float fast_tanh(float x) {
    x = fminf(x, 8.0f);
    float e = __expf(2.0f * x);
    return (e - 1.0f) * __builtin_amdgcn_rcpf(e + 1.0f);
}

__global__ __attribute__((amdgpu_flat_work_group_size(1024, 1024),
                          amdgpu_waves_per_eu(4, 4)))
void gru_scan_kernel(
    const float* __restrict__ xp,    // [T*B, 768] (b_ih + r/z b_hh folded)
    const float* __restrict__ W_hh,  // [768, 256]
    const float* __restrict__ b_hh,  // [768]
    float* __restrict__ out)         // outputs [T*B*256] ++ h_last [64*256]
{
    const int b   = blockIdx.x;    // batch element
    const int tid = threadIdx.x;
    const int jj  = tid >> 3;      // 0..127 : column pair (jj, jj+128)
    const int q   = tid & 7;       // k-slice [32q, 32q+32)
    const int rot = (q >> 1) & 3;  // chunk rotation for bank-conflict-free LDS

    __shared__ __align__(16) _Float16 hs[2][H_DIM];  // double-buffered h (f16)

    // ---- prologue: weights -> 96 registers, f16-packed, chunk-rotated ----
    // w[(c*6+s)*4+m] = W_hh[jj+128s][32q + 8*cc(c) + 2m .. +1], cc = (c+rot)&3
    uint32_t w[96];
    #pragma unroll
    for (int c = 0; c < 4; ++c) {
        const int cc = (c + rot) & 3;
        #pragma unroll
        for (int s = 0; s < 6; ++s) {
            const float* wr = W_hh + (size_t)(jj + 128 * s) * H_DIM + q * 32 + cc * 8;
            float4 f0 = *reinterpret_cast<const float4*>(wr);
            float4 f1 = *reinterpret_cast<const float4*>(wr + 4);
            w[(c*6+s)*4+0] = __builtin_bit_cast(uint32_t, half2v{(_Float16)f0.x, (_Float16)f0.y});
            w[(c*6+s)*4+1] = __builtin_bit_cast(uint32_t, half2v{(_Float16)f0.z, (_Float16)f0.w});
            w[(c*6+s)*4+2] = __builtin_bit_cast(uint32_t, half2v{(_Float16)f1.x, (_Float16)f1.y});
            w[(c*6+s)*4+3] = __builtin_bit_cast(uint32_t, half2v{(_Float16)f1.z, (_Float16)f1.w});
        }
    }
    // Opacity pin: prevents remat of the loads inside the t-loop.
    #pragma unroll
    for (int i = 0; i < 96; ++i)
        asm volatile("" : "+v"(w[i]));

    // only the n-gate b_hh part stays in-kernel (multiplied by r)
    const float bn0 = b_hh[512 + jj];
    const float bn1 = b_hh[512 + jj + 128];

    if (tid < 32) reinterpret_cast<uint4*>(hs[0])[tid] = uint4{0, 0, 0, 0};
    __syncthreads();

    const int c0 = jj, c1 = jj + 128;
    float h0 = 0.0f, h1 = 0.0f;

    #define WH(i) __builtin_bit_cast(half2v, w[i])

    for (int t = 0; t < T_SEQ; ++t) {
        const float* xrow = xp + ((size_t)t * B_SZ + b) * G3;
        const float xr0 = xrow[c0],       xr1 = xrow[c1];
        const float xz0 = xrow[256 + c0], xz1 = xrow[256 + c1];
        const float xn0 = xrow[512 + c0], xn1 = xrow[512 + c1];

        float a0 = 0.f, a1 = 0.f, a2 = 0.f, a3 = 0.f, a4 = 0.f, a5 = 0.f;
        const char* hbase = reinterpret_cast<const char*>(&hs[t & 1][0]) + q * 64;
        #pragma unroll
        for (int c = 0; c < 4; ++c) {
            const int cc = (c + rot) & 3;
            const uint4 hv = *reinterpret_cast<const uint4*>(hbase + cc * 16);
            const half2v p0 = __builtin_bit_cast(half2v, hv.x);
            const half2v p1 = __builtin_bit_cast(half2v, hv.y);
            const half2v p2 = __builtin_bit_cast(half2v, hv.z);
            const half2v p3 = __builtin_bit_cast(half2v, hv.w);
            const int base = c * 24;
            a0 = FDOT2(WH(base+ 0), p0, a0); a0 = FDOT2(WH(base+ 1), p1, a0);
            a0 = FDOT2(WH(base+ 2), p2, a0); a0 = FDOT2(WH(base+ 3), p3, a0);
            a1 = FDOT2(WH(base+ 4), p0, a1); a1 = FDOT2(WH(base+ 5), p1, a1);
            a1 = FDOT2(WH(base+ 6), p2, a1); a1 = FDOT2(WH(base+ 7), p3, a1);
            a2 = FDOT2(WH(base+ 8), p0, a2); a2 = FDOT2(WH(base+ 9), p1, a2);
            a2 = FDOT2(WH(base+10), p2, a2); a2 = FDOT2(WH(base+11), p3, a2);
            a3 = FDOT2(WH(base+12), p0, a3); a3 = FDOT2(WH(base+13), p1, a3);
            a3 = FDOT2(WH(base+14), p2, a3); a3 = FDOT2(WH(base+15), p3, a3);
            a4 = FDOT2(WH(base+16), p0, a4); a4 = FDOT2(WH(base+17), p1, a4);
            a4 = FDOT2(WH(base+18), p2, a4); a4 = FDOT2(WH(base+19), p3, a4);
            a5 = FDOT2(WH(base+20), p0, a5); a5 = FDOT2(WH(base+21), p1, a5);
            a5 = FDOT2(WH(base+22), p2, a5); a5 = FDOT2(WH(base+23), p3, a5);
        }

        // ---- 8-lane butterfly reduce (within q-group) ----
        a0 += __shfl_xor(a0, 1); a0 += __shfl_xor(a0, 2); a0 += __shfl_xor(a0, 4);
        a1 += __shfl_xor(a1, 1); a1 += __shfl_xor(a1, 2); a1 += __shfl_xor(a1, 4);
        a2 += __shfl_xor(a2, 1); a2 += __shfl_xor(a2, 2); a2 += __shfl_xor(a2, 4);
        a3 += __shfl_xor(a3, 1); a3 += __shfl_xor(a3, 2); a3 += __shfl_xor(a3, 4);
        a4 += __shfl_xor(a4, 1); a4 += __shfl_xor(a4, 2); a4 += __shfl_xor(a4, 4);
        a5 += __shfl_xor(a5, 1); a5 += __shfl_xor(a5, 2); a5 += __shfl_xor(a5, 4);

        // xp already contains b_ih (+ b_hh for r/z); n-gate b_hh inside r*(.)
        const float r0 = fast_sigmoid(xr0 + a0);
        const float r1 = fast_sigmoid(xr1 + a1);
        const float z0 = fast_sigmoid(xz0 + a2);
        const float z1 = fast_sigmoid(xz1 + a3);
        const float n0 = fast_tanh(xn0 + r0 * (a4 + bn0));
        const float n1 = fast_tanh(xn1 + r1 * (a5 + bn1));
        h0 = (1.0f - z0) * n0 + z0 * h0;
        h1 = (1.0f - z1) * n1 + z1 * h1;

        if (q == 0) {
            float* orow = out + ((size_t)t * B_SZ + b) * H_DIM;
            orow[c0] = h0;
            orow[c1] = h1;
            hs[(t + 1) & 1][c0] = (_Float16)h0;
            hs[(t + 1) & 1][c1] = (_Float16)h1;
        }
        __syncthreads();   // hs[(t+1)&1] visible; hs[t&1] free for overwrite
    }

    if (q == 0) {
        float* hl = out + (size_t)T_SEQ * B_SZ * H_DIM + (size_t)b * H_DIM;
        hl[c0] = h0;
        hl[c1] = h1;
    }
    #undef WH
}

extern "C" void kernel_launch(void* const* d_in, const int* in_sizes, int n_in,
                              void* d_out, int out_size, void* d_ws, size_t ws_size,
                              hipStream_t stream) {
    const int*   input = (const int*)d_in[0];
    const float* emb   = (const float*)d_in[1];
    const float* W_ih  = (const float*)d_in[2];
    const float* W_hh  = (const float*)d_in[3];
    const float* b_ih  = (const float*)d_in[4];
    const float* b_hh  = (const float*)d_in[5];
    float* out = (float*)d_out;

    float* xp = (float*)d_ws;   // [T*B, 768] floats

    dim3 gridA(T_SEQ * B_SZ / BM, G3 / BN);   // (512, 12)
    xproj_kernel<<<gridA, 256, 0, stream>>>(input, emb, W_ih, b_ih, b_hh, xp);

    gru_scan_kernel<<<B_SZ, 1024, 0, stream>>>(xp, W_hh, b_hh, out);
}